// Round 1
// baseline (529.040 us; speedup 1.0000x reference)
//
#include <hip/hip_runtime.h>
#include <cstdint>

// MultiHeadAttention with LoRA on Q/V.  B=4,S=2048,D=1024,H=16,HD=64,RANK=16,scale=2.0
// Strategy: fold LoRA into effective weights (W + 2*B@A), bf16 MFMA GEMMs for
// projections, flash-style online-softmax attention, bf16 compute / fp32 accum.

#define D_DIM 1024
#define S_DIM 2048
#define B_DIM 4
#define H_DIM 16
#define HD_DIM 64
#define M_DIM (B_DIM * S_DIM)  // 8192 rows

typedef __bf16 bf16;
typedef __bf16 bf16x8 __attribute__((ext_vector_type(8)));
typedef float f32x4 __attribute__((ext_vector_type(4)));

typedef __attribute__((address_space(1))) void* as1p;
typedef __attribute__((address_space(3))) void* as3p;

// async global->LDS, 16B per lane.  LDS dest must equal wave-base + lane*16.
__device__ __forceinline__ void gll16(const void* g, void* l) {
  __builtin_amdgcn_global_load_lds((as1p)(g), (as3p)(l), 16, 0, 0);
}

// ---------------------------------------------------------------- conv x -> bf16
__global__ void convert_x_kernel(const float* __restrict__ x, bf16* __restrict__ xb) {
  const int i = (blockIdx.x * 256 + threadIdx.x) * 8;
  const float4 a = *(const float4*)(x + i);
  const float4 b = *(const float4*)(x + i + 4);
  bf16x8 o;
  o[0] = (bf16)a.x; o[1] = (bf16)a.y; o[2] = (bf16)a.z; o[3] = (bf16)a.w;
  o[4] = (bf16)b.x; o[5] = (bf16)b.y; o[6] = (bf16)b.z; o[7] = (bf16)b.w;
  *(bf16x8*)(xb + i) = o;
}

// ------------------------------------------------- W_eff = W + 2*Bm@A  -> bf16
__global__ void prep_w_kernel(const float* __restrict__ W, const float* __restrict__ A,
                              const float* __restrict__ Bm, bf16* __restrict__ out,
                              int use_lora) {
  const int i = blockIdx.x * 256 + threadIdx.x;  // over 1024*1024
  const int n = i >> 10, k = i & (D_DIM - 1);
  float w = W[i];
  if (use_lora) {
    float acc = 0.f;
#pragma unroll
    for (int r = 0; r < 16; ++r) acc = fmaf(Bm[n * 16 + r], A[r * D_DIM + k], acc);
    w += 2.0f * acc;  // SCALING = 32/16
  }
  out[i] = (bf16)w;
}

// --------------------------------------------------------------- GEMM  Y = X W^T + b
// X [M,1024] bf16 row-major, W [1024,1024] bf16 row-major (N,K), bias fp32.
// MODE 0: out bf16 [B,H,S,HD]   (Q,K layout)
// MODE 2: out bf16 [B,H,HD,S]   (V transposed for attention)
// MODE 1: out fp32 [M,1024]     (final output)
template <int MODE>
__global__ __launch_bounds__(256) void gemm_nt_kernel(const bf16* __restrict__ X,
                                                      const bf16* __restrict__ W,
                                                      const float* __restrict__ bias,
                                                      void* __restrict__ out) {
  __shared__ __attribute__((aligned(16))) bf16 As[128 * 64];
  __shared__ __attribute__((aligned(16))) bf16 Bs[128 * 64];
  const int tid = threadIdx.x;
  const int wave = tid >> 6, lane = tid & 63;
  const int quad = lane >> 4, l16 = lane & 15;
  const int m0 = blockIdx.x * 128, n0 = blockIdx.y * 128;
  const int wm = (wave >> 1) * 64, wn = (wave & 1) * 64;
  const int srow = lane >> 3;        // staging: 8 lanes per row
  const int skb = (lane & 7) * 8;    // staging: element offset in row

  const f32x4 zero = {0.f, 0.f, 0.f, 0.f};
  f32x4 acc[4][4];
#pragma unroll
  for (int mi = 0; mi < 4; ++mi)
#pragma unroll
    for (int ni = 0; ni < 4; ++ni) acc[mi][ni] = zero;

  for (int kt = 0; kt < D_DIM / 64; ++kt) {
    __syncthreads();
    const int kb = kt * 64;
#pragma unroll
    for (int it = 0; it < 4; ++it) {
      const int c = it * 4 + wave;          // chunk 0..15, 1024B each
      const int row = c * 8 + srow;
      gll16(X + (size_t)(m0 + row) * D_DIM + kb + skb, As + c * 512 + lane * 8);
      gll16(W + (size_t)(n0 + row) * D_DIM + kb + skb, Bs + c * 512 + lane * 8);
    }
    __syncthreads();
#pragma unroll
    for (int ks = 0; ks < 2; ++ks) {
      const int ko = ks * 32 + quad * 8;
      bf16x8 af[4], bfr[4];
#pragma unroll
      for (int mi = 0; mi < 4; ++mi)
        af[mi] = *(const bf16x8*)(As + (wm + mi * 16 + l16) * 64 + ko);
#pragma unroll
      for (int ni = 0; ni < 4; ++ni)
        bfr[ni] = *(const bf16x8*)(Bs + (wn + ni * 16 + l16) * 64 + ko);
#pragma unroll
      for (int mi = 0; mi < 4; ++mi)
#pragma unroll
        for (int ni = 0; ni < 4; ++ni)
          acc[mi][ni] =
              __builtin_amdgcn_mfma_f32_16x16x32_bf16(af[mi], bfr[ni], acc[mi][ni], 0, 0, 0);
    }
  }

  // epilogue: C/D layout col=l16, row=quad*4+reg
#pragma unroll
  for (int ni = 0; ni < 4; ++ni) {
    const int col = n0 + wn + ni * 16 + l16;
    const float bv = bias[col];
#pragma unroll
    for (int mi = 0; mi < 4; ++mi) {
#pragma unroll
      for (int r = 0; r < 4; ++r) {
        const int row = m0 + wm + mi * 16 + quad * 4 + r;
        const float v = acc[mi][ni][r] + bv;
        if (MODE == 1) {
          ((float*)out)[(size_t)row * D_DIM + col] = v;
        } else {
          const int b = row >> 11, s = row & (S_DIM - 1);
          const int h = col >> 6, hd = col & 63;
          if (MODE == 0)
            ((bf16*)out)[((size_t)(b * H_DIM + h) * S_DIM + s) * HD_DIM + hd] = (bf16)v;
          else
            ((bf16*)out)[((size_t)(b * H_DIM + h) * HD_DIM + hd) * S_DIM + s] = (bf16)v;
        }
      }
    }
  }
}

// ------------------------------------------------------------------ attention
// Q,K [B,H,S,64] bf16; Vt [B,H,64,S] bf16; mask [B,S] fp32; ctx [B,S,D] bf16.
// Block: 128 Q rows (4 waves x 32 rows), KV tile 64, online softmax.
__global__ __launch_bounds__(256) void attn_kernel(const bf16* __restrict__ Q,
                                                   const bf16* __restrict__ K,
                                                   const bf16* __restrict__ Vt,
                                                   const float* __restrict__ mask,
                                                   bf16* __restrict__ ctx) {
  __shared__ __attribute__((aligned(16))) bf16 Qs[128 * 64];   // [qrow][hd]
  __shared__ __attribute__((aligned(16))) bf16 Ks[64 * 64];    // [kv][hd]
  __shared__ __attribute__((aligned(16))) bf16 Vs[64 * 64];    // [hd][kv]
  __shared__ __attribute__((aligned(16))) bf16 Ps[4][32 * 64]; // per-wave P

  const int tid = threadIdx.x;
  const int wave = tid >> 6, lane = tid & 63;
  const int quad = lane >> 4, l16 = lane & 15;
  const int bh = blockIdx.y, b = bh >> 4, h = bh & 15;
  const int qt = blockIdx.x;

  const bf16* Qg = Q + ((size_t)bh * S_DIM + qt * 128) * HD_DIM;
  const bf16* Kg = K + (size_t)bh * S_DIM * HD_DIM;
  const bf16* Vg = Vt + (size_t)bh * HD_DIM * S_DIM;

  // stage Q tile once: 16 chunks of 1024B
#pragma unroll
  for (int it = 0; it < 4; ++it) {
    const int c = it * 4 + wave;
    gll16(Qg + (size_t)(c * 8 + (lane >> 3)) * HD_DIM + (lane & 7) * 8,
          Qs + c * 512 + lane * 8);
  }

  const f32x4 zero = {0.f, 0.f, 0.f, 0.f};
  f32x4 o[2][4];
  float mrow[2][4], lrow[2][4];
#pragma unroll
  for (int mi = 0; mi < 2; ++mi) {
#pragma unroll
    for (int ni = 0; ni < 4; ++ni) o[mi][ni] = zero;
#pragma unroll
    for (int r = 0; r < 4; ++r) { mrow[mi][r] = -1e30f; lrow[mi][r] = 0.f; }
  }

  for (int t = 0; t < S_DIM / 64; ++t) {
    __syncthreads();
    // stage K [64][64] and Vt [64][64]: 8 chunks each
#pragma unroll
    for (int it = 0; it < 2; ++it) {
      const int c = it * 4 + wave;
      gll16(Kg + (size_t)(t * 64 + c * 8 + (lane >> 3)) * HD_DIM + (lane & 7) * 8,
            Ks + c * 512 + lane * 8);
      gll16(Vg + (size_t)(c * 8 + (lane >> 3)) * S_DIM + t * 64 + (lane & 7) * 8,
            Vs + c * 512 + lane * 8);
    }
    __syncthreads();

    // S = Q K^T : per wave 32 q-rows x 64 kv
    f32x4 sc[2][4];
#pragma unroll
    for (int mi = 0; mi < 2; ++mi)
#pragma unroll
      for (int ni = 0; ni < 4; ++ni) sc[mi][ni] = zero;
#pragma unroll
    for (int ks = 0; ks < 2; ++ks) {
      const int ko = ks * 32 + quad * 8;
      bf16x8 qf[2];
      qf[0] = *(const bf16x8*)(Qs + (wave * 32 + l16) * 64 + ko);
      qf[1] = *(const bf16x8*)(Qs + (wave * 32 + 16 + l16) * 64 + ko);
#pragma unroll
      for (int ni = 0; ni < 4; ++ni) {
        const bf16x8 kf = *(const bf16x8*)(Ks + (ni * 16 + l16) * 64 + ko);
        sc[0][ni] = __builtin_amdgcn_mfma_f32_16x16x32_bf16(qf[0], kf, sc[0][ni], 0, 0, 0);
        sc[1][ni] = __builtin_amdgcn_mfma_f32_16x16x32_bf16(qf[1], kf, sc[1][ni], 0, 0, 0);
      }
    }

    // scale + mask + running max
    float mnew[2][4];
#pragma unroll
    for (int mi = 0; mi < 2; ++mi)
#pragma unroll
      for (int r = 0; r < 4; ++r) mnew[mi][r] = mrow[mi][r];
#pragma unroll
    for (int ni = 0; ni < 4; ++ni) {
      const float mk = mask[b * S_DIM + t * 64 + ni * 16 + l16];
#pragma unroll
      for (int mi = 0; mi < 2; ++mi)
#pragma unroll
        for (int r = 0; r < 4; ++r) {
          const float v = sc[mi][ni][r] * 0.125f + mk;
          sc[mi][ni][r] = v;
          mnew[mi][r] = fmaxf(mnew[mi][r], v);
        }
    }
#pragma unroll
    for (int mi = 0; mi < 2; ++mi)
#pragma unroll
      for (int r = 0; r < 4; ++r) {
        float v = mnew[mi][r];
        v = fmaxf(v, __shfl_xor(v, 1, 64));
        v = fmaxf(v, __shfl_xor(v, 2, 64));
        v = fmaxf(v, __shfl_xor(v, 4, 64));
        v = fmaxf(v, __shfl_xor(v, 8, 64));
        mnew[mi][r] = v;
      }

    float alpha[2][4], rsum[2][4];
#pragma unroll
    for (int mi = 0; mi < 2; ++mi)
#pragma unroll
      for (int r = 0; r < 4; ++r) {
        alpha[mi][r] = __expf(mrow[mi][r] - mnew[mi][r]);
        mrow[mi][r] = mnew[mi][r];
        rsum[mi][r] = 0.f;
      }
#pragma unroll
    for (int ni = 0; ni < 4; ++ni)
#pragma unroll
      for (int mi = 0; mi < 2; ++mi)
#pragma unroll
        for (int r = 0; r < 4; ++r) {
          const float p = __expf(sc[mi][ni][r] - mnew[mi][r]);
          sc[mi][ni][r] = p;
          rsum[mi][r] += p;
        }
#pragma unroll
    for (int mi = 0; mi < 2; ++mi)
#pragma unroll
      for (int r = 0; r < 4; ++r) {
        float v = rsum[mi][r];
        v += __shfl_xor(v, 1, 64);
        v += __shfl_xor(v, 2, 64);
        v += __shfl_xor(v, 4, 64);
        v += __shfl_xor(v, 8, 64);
        lrow[mi][r] = lrow[mi][r] * alpha[mi][r] + v;
      }
#pragma unroll
    for (int mi = 0; mi < 2; ++mi)
#pragma unroll
      for (int ni = 0; ni < 4; ++ni)
#pragma unroll
        for (int r = 0; r < 4; ++r) o[mi][ni][r] *= alpha[mi][r];

    // P: C-layout -> LDS (per-wave region) -> A-layout
    bf16* pw = &Ps[wave][0];
#pragma unroll
    for (int mi = 0; mi < 2; ++mi)
#pragma unroll
      for (int ni = 0; ni < 4; ++ni)
#pragma unroll
        for (int r = 0; r < 4; ++r)
          pw[(mi * 16 + quad * 4 + r) * 64 + ni * 16 + l16] = (bf16)sc[mi][ni][r];
    __syncthreads();  // lgkmcnt drain: P writes visible before reads

    // O += P V
#pragma unroll
    for (int ks = 0; ks < 2; ++ks) {
      const int ko = ks * 32 + quad * 8;
      bf16x8 pf[2];
      pf[0] = *(const bf16x8*)(pw + l16 * 64 + ko);
      pf[1] = *(const bf16x8*)(pw + (16 + l16) * 64 + ko);
#pragma unroll
      for (int ni = 0; ni < 4; ++ni) {
        const bf16x8 vf = *(const bf16x8*)(Vs + (ni * 16 + l16) * 64 + ko);
        o[0][ni] = __builtin_amdgcn_mfma_f32_16x16x32_bf16(pf[0], vf, o[0][ni], 0, 0, 0);
        o[1][ni] = __builtin_amdgcn_mfma_f32_16x16x32_bf16(pf[1], vf, o[1][ni], 0, 0, 0);
      }
    }
  }

  // epilogue: divide by l, store ctx[b][s][h*64+hd] bf16
#pragma unroll
  for (int mi = 0; mi < 2; ++mi)
#pragma unroll
    for (int ni = 0; ni < 4; ++ni)
#pragma unroll
      for (int r = 0; r < 4; ++r) {
        const int s = qt * 128 + wave * 32 + mi * 16 + quad * 4 + r;
        const float v = o[mi][ni][r] / lrow[mi][r];
        ctx[((size_t)b * S_DIM + s) * D_DIM + h * 64 + ni * 16 + l16] = (bf16)v;
      }
}

// ------------------------------------------------------------------ launch
extern "C" void kernel_launch(void* const* d_in, const int* in_sizes, int n_in,
                              void* d_out, int out_size, void* d_ws, size_t ws_size,
                              hipStream_t stream) {
  const float* x    = (const float*)d_in[0];
  const float* mask = (const float*)d_in[1];
  const float* Wq   = (const float*)d_in[2];
  const float* bq   = (const float*)d_in[3];
  const float* Aq   = (const float*)d_in[4];
  const float* Bq   = (const float*)d_in[5];
  const float* Wk   = (const float*)d_in[6];
  const float* bk   = (const float*)d_in[7];
  const float* Wv   = (const float*)d_in[8];
  const float* bv   = (const float*)d_in[9];
  const float* Av   = (const float*)d_in[10];
  const float* Bv   = (const float*)d_in[11];
  const float* Wo   = (const float*)d_in[12];
  const float* bo   = (const float*)d_in[13];
  float* out = (float*)d_out;

  // workspace layout (88 MB total)
  bf16* xb = (bf16*)d_ws;                       // 16 MB
  bf16* wq = xb + (size_t)M_DIM * D_DIM;        // 2 MB each
  bf16* wk = wq + (size_t)D_DIM * D_DIM;
  bf16* wv = wk + (size_t)D_DIM * D_DIM;
  bf16* wo = wv + (size_t)D_DIM * D_DIM;
  bf16* Qw = wo + (size_t)D_DIM * D_DIM;        // 16 MB each
  bf16* Kw = Qw + (size_t)M_DIM * D_DIM;
  bf16* Vw = Kw + (size_t)M_DIM * D_DIM;
  bf16* Cw = Vw + (size_t)M_DIM * D_DIM;

  convert_x_kernel<<<M_DIM * D_DIM / (256 * 8), 256, 0, stream>>>(x, xb);
  prep_w_kernel<<<D_DIM * D_DIM / 256, 256, 0, stream>>>(Wq, Aq, Bq, wq, 1);
  prep_w_kernel<<<D_DIM * D_DIM / 256, 256, 0, stream>>>(Wk, nullptr, nullptr, wk, 0);
  prep_w_kernel<<<D_DIM * D_DIM / 256, 256, 0, stream>>>(Wv, Av, Bv, wv, 1);
  prep_w_kernel<<<D_DIM * D_DIM / 256, 256, 0, stream>>>(Wo, nullptr, nullptr, wo, 0);

  gemm_nt_kernel<0><<<dim3(M_DIM / 128, D_DIM / 128), 256, 0, stream>>>(xb, wq, bq, Qw);
  gemm_nt_kernel<0><<<dim3(M_DIM / 128, D_DIM / 128), 256, 0, stream>>>(xb, wk, bk, Kw);
  gemm_nt_kernel<2><<<dim3(M_DIM / 128, D_DIM / 128), 256, 0, stream>>>(xb, wv, bv, Vw);

  attn_kernel<<<dim3(S_DIM / 128, B_DIM * H_DIM), 256, 0, stream>>>(Qw, Kw, Vw, mask, Cw);

  gemm_nt_kernel<1><<<dim3(M_DIM / 128, D_DIM / 128), 256, 0, stream>>>(Cw, wo, bo, out);
}

// Round 2
// 397.334 us; speedup vs baseline: 1.3315x; 1.3315x over previous
//
#include <hip/hip_runtime.h>
#include <cstdint>

// MultiHeadAttention with LoRA on Q/V.  B=4,S=2048,D=1024,H=16,HD=64,RANK=16,scale=2.0
// R2: attention rebuilt — fixed-shift softmax (no max/sum shuffles; row-sum via
// MFMA with all-ones B fragment), XOR-swizzled LDS (conflict-free), Q in regs,
// KV tile 128, per-wave P with no extra barrier.  GEMMs gain the same swizzle.

#define D_DIM 1024
#define S_DIM 2048
#define B_DIM 4
#define H_DIM 16
#define HD_DIM 64
#define M_DIM (B_DIM * S_DIM)  // 8192 rows

typedef __bf16 bf16;
typedef __bf16 bf16x8 __attribute__((ext_vector_type(8)));
typedef float f32x4 __attribute__((ext_vector_type(4)));

typedef __attribute__((address_space(1))) void* as1p;
typedef __attribute__((address_space(3))) void* as3p;

__device__ __forceinline__ void gll16(const void* g, void* l) {
  __builtin_amdgcn_global_load_lds((as1p)(g), (as3p)(l), 16, 0, 0);
}

// ---------------------------------------------------------------- conv x -> bf16
__global__ void convert_x_kernel(const float* __restrict__ x, bf16* __restrict__ xb) {
  const int i = (blockIdx.x * 256 + threadIdx.x) * 8;
  const float4 a = *(const float4*)(x + i);
  const float4 b = *(const float4*)(x + i + 4);
  bf16x8 o;
  o[0] = (bf16)a.x; o[1] = (bf16)a.y; o[2] = (bf16)a.z; o[3] = (bf16)a.w;
  o[4] = (bf16)b.x; o[5] = (bf16)b.y; o[6] = (bf16)b.z; o[7] = (bf16)b.w;
  *(bf16x8*)(xb + i) = o;
}

// ------------------------------------------------- W_eff = W + 2*Bm@A  -> bf16
__global__ void prep_w_kernel(const float* __restrict__ W, const float* __restrict__ A,
                              const float* __restrict__ Bm, bf16* __restrict__ out,
                              int use_lora) {
  const int i = blockIdx.x * 256 + threadIdx.x;  // over 1024*1024
  const int n = i >> 10, k = i & (D_DIM - 1);
  float w = W[i];
  if (use_lora) {
    float acc = 0.f;
#pragma unroll
    for (int r = 0; r < 16; ++r) acc = fmaf(Bm[n * 16 + r], A[r * D_DIM + k], acc);
    w += 2.0f * acc;  // SCALING = 32/16
  }
  out[i] = (bf16)w;
}

// --------------------------------------------------------------- GEMM  Y = X W^T + b
// XOR-swizzled LDS: 16B block index ^= (row & 7).  global_load_lds permits
// per-lane global source permutation; only the LDS dest is lane-linear.
template <int MODE>
__global__ __launch_bounds__(256) void gemm_nt_kernel(const bf16* __restrict__ X,
                                                      const bf16* __restrict__ W,
                                                      const float* __restrict__ bias,
                                                      void* __restrict__ out) {
  __shared__ __attribute__((aligned(16))) bf16 As[128 * 64];
  __shared__ __attribute__((aligned(16))) bf16 Bs[128 * 64];
  const int tid = threadIdx.x;
  const int wave = tid >> 6, lane = tid & 63;
  const int quad = lane >> 4, l16 = lane & 15;
  const int m0 = blockIdx.x * 128, n0 = blockIdx.y * 128;
  const int wm = (wave >> 1) * 64, wn = (wave & 1) * 64;
  const int srow = lane >> 3;        // staging: 8 lanes per row
  const int sblk = (lane & 7);       // staging: 16B block slot within row

  const f32x4 zero = {0.f, 0.f, 0.f, 0.f};
  f32x4 acc[4][4];
#pragma unroll
  for (int mi = 0; mi < 4; ++mi)
#pragma unroll
    for (int ni = 0; ni < 4; ++ni) acc[mi][ni] = zero;

  for (int kt = 0; kt < D_DIM / 64; ++kt) {
    __syncthreads();
    const int kb = kt * 64;
#pragma unroll
    for (int it = 0; it < 4; ++it) {
      const int c = it * 4 + wave;          // chunk 0..15, 1024B each
      const int row = c * 8 + srow;
      const int b = sblk ^ (row & 7);       // logical 16B block fetched
      gll16(X + (size_t)(m0 + row) * D_DIM + kb + b * 8, As + c * 512 + lane * 8);
      gll16(W + (size_t)(n0 + row) * D_DIM + kb + b * 8, Bs + c * 512 + lane * 8);
    }
    __syncthreads();
#pragma unroll
    for (int ks = 0; ks < 2; ++ks) {
      bf16x8 af[4], bfr[4];
#pragma unroll
      for (int mi = 0; mi < 4; ++mi) {
        const int row = wm + mi * 16 + l16;
        af[mi] = *(const bf16x8*)(As + row * 64 + (((ks * 4 + quad) ^ (row & 7)) * 8));
      }
#pragma unroll
      for (int ni = 0; ni < 4; ++ni) {
        const int row = wn + ni * 16 + l16;
        bfr[ni] = *(const bf16x8*)(Bs + row * 64 + (((ks * 4 + quad) ^ (row & 7)) * 8));
      }
#pragma unroll
      for (int mi = 0; mi < 4; ++mi)
#pragma unroll
        for (int ni = 0; ni < 4; ++ni)
          acc[mi][ni] =
              __builtin_amdgcn_mfma_f32_16x16x32_bf16(af[mi], bfr[ni], acc[mi][ni], 0, 0, 0);
    }
  }

  // epilogue: C/D layout col=l16, row=quad*4+reg
#pragma unroll
  for (int ni = 0; ni < 4; ++ni) {
    const int col = n0 + wn + ni * 16 + l16;
    const float bv = bias[col];
#pragma unroll
    for (int mi = 0; mi < 4; ++mi) {
#pragma unroll
      for (int r = 0; r < 4; ++r) {
        const int row = m0 + wm + mi * 16 + quad * 4 + r;
        const float v = acc[mi][ni][r] + bv;
        if (MODE == 1) {
          ((float*)out)[(size_t)row * D_DIM + col] = v;
        } else {
          const int b = row >> 11, s = row & (S_DIM - 1);
          const int h = col >> 6, hd = col & 63;
          if (MODE == 0)
            ((bf16*)out)[((size_t)(b * H_DIM + h) * S_DIM + s) * HD_DIM + hd] = (bf16)v;
          else
            ((bf16*)out)[((size_t)(b * H_DIM + h) * HD_DIM + hd) * S_DIM + s] = (bf16)v;
        }
      }
    }
  }
}

// ------------------------------------------------------------------ attention
// Q,K [B,H,S,64] bf16; Vt [B,H,64,S] bf16; mask [B,S] fp32; ctx [B,S,D] bf16.
// 128 Q rows/block (4 waves x 32), KV tile 128, fixed-shift softmax:
//   p = exp(s*0.125 + mask - 11.09),  out = (P V) / (P 1)  — shift cancels.
// Row-sum computed by MFMA against an all-ones B fragment: lands in the same
// lane/reg as o, so the final divide is lane-local (zero shuffles).
__global__ __launch_bounds__(256, 3) void attn_kernel(const bf16* __restrict__ Q,
                                                      const bf16* __restrict__ K,
                                                      const bf16* __restrict__ Vt,
                                                      const float* __restrict__ mask,
                                                      bf16* __restrict__ ctx) {
  __shared__ __attribute__((aligned(16))) bf16 Ks[128 * 64];    // [kv][hd] swz
  __shared__ __attribute__((aligned(16))) bf16 Vs[64 * 128];    // [hd][kv] swz
  __shared__ __attribute__((aligned(16))) bf16 Ps[4][32 * 64];  // per-wave P swz

  const int tid = threadIdx.x;
  const int wave = tid >> 6, lane = tid & 63;
  const int quad = lane >> 4, l16 = lane & 15;
  const int bh = blockIdx.y, b = bh >> 4, h = bh & 15;
  const int qt = blockIdx.x;

  // Q fragments live in registers for the whole kernel (wave-private rows).
  const bf16* Qg = Q + ((size_t)bh * S_DIM + qt * 128 + wave * 32) * HD_DIM;
  bf16x8 qf[2][2];
#pragma unroll
  for (int mi = 0; mi < 2; ++mi)
#pragma unroll
    for (int ks = 0; ks < 2; ++ks)
      qf[mi][ks] = *(const bf16x8*)(Qg + (mi * 16 + l16) * HD_DIM + ks * 32 + quad * 8);

  bf16x8 onef;
#pragma unroll
  for (int j = 0; j < 8; ++j) onef[j] = (bf16)1.0f;

  const f32x4 zero = {0.f, 0.f, 0.f, 0.f};
  f32x4 o[2][4], osum[2];
#pragma unroll
  for (int mi = 0; mi < 2; ++mi) {
    osum[mi] = zero;
#pragma unroll
    for (int ni = 0; ni < 4; ++ni) o[mi][ni] = zero;
  }

  const bf16* Kg0 = K + (size_t)bh * S_DIM * HD_DIM;
  const bf16* Vg0 = Vt + (size_t)bh * HD_DIM * S_DIM;
  const float* mrow = mask + b * S_DIM;
  const float MSHIFT = 11.0903548f;  // 16*ln2; cancels in o/osum

  for (int t = 0; t < S_DIM / 128; ++t) {
    __syncthreads();
    const bf16* Kg = Kg0 + (size_t)t * 128 * HD_DIM;
    const bf16* Vg = Vg0 + t * 128;
#pragma unroll
    for (int it = 0; it < 4; ++it) {
      const int c = it * 4 + wave;
      {  // K tile [128][64], rows of 8 blocks, swz ^(row&7)
        const int row = c * 8 + (lane >> 3);
        const int bb = (lane & 7) ^ (row & 7);
        gll16(Kg + (size_t)row * HD_DIM + bb * 8, Ks + c * 512 + lane * 8);
      }
      {  // V tile [64][128], rows of 16 blocks, swz ^(row&15)
        const int row = c * 4 + (lane >> 4);
        const int bb = (lane & 15) ^ (row & 15);
        gll16(Vg + (size_t)row * S_DIM + bb * 8, Vs + c * 512 + lane * 8);
      }
    }
    __syncthreads();

    bf16* pw = &Ps[wave][0];
#pragma unroll
    for (int half = 0; half < 2; ++half) {
      // ---- S = Q K^T for kv = half*64 .. +63
      f32x4 sc[2][4];
#pragma unroll
      for (int mi = 0; mi < 2; ++mi)
#pragma unroll
        for (int ni = 0; ni < 4; ++ni) sc[mi][ni] = zero;
#pragma unroll
      for (int ks = 0; ks < 2; ++ks) {
#pragma unroll
        for (int ni = 0; ni < 4; ++ni) {
          const int row = half * 64 + ni * 16 + l16;
          const bf16x8 kf =
              *(const bf16x8*)(Ks + row * 64 + (((ks * 4 + quad) ^ (row & 7)) * 8));
          sc[0][ni] = __builtin_amdgcn_mfma_f32_16x16x32_bf16(qf[0][ks], kf, sc[0][ni], 0, 0, 0);
          sc[1][ni] = __builtin_amdgcn_mfma_f32_16x16x32_bf16(qf[1][ks], kf, sc[1][ni], 0, 0, 0);
        }
      }

      // ---- p = exp(s/8 + mask - MSHIFT); write P (swizzled, per-wave region)
#pragma unroll
      for (int ni = 0; ni < 4; ++ni) {
        const float cm = mrow[t * 128 + half * 64 + ni * 16 + l16] - MSHIFT;
        const int pcol = ni * 16 + l16;
#pragma unroll
        for (int mi = 0; mi < 2; ++mi)
#pragma unroll
          for (int r = 0; r < 4; ++r) {
            const float p = __expf(fmaf(sc[mi][ni][r], 0.125f, cm));
            const int prow = mi * 16 + quad * 4 + r;
            pw[prow * 64 + (((pcol >> 3) ^ (prow & 7)) * 8) + (pcol & 7)] = (bf16)p;
          }
      }
      // producer == consumer wave: DS ops are in-order per wave; compiler
      // inserts the lgkmcnt wait (same __shared__ array, may-alias).

      // ---- O += P V ; osum += P 1
#pragma unroll
      for (int ks = 0; ks < 2; ++ks) {
        bf16x8 pf[2];
#pragma unroll
        for (int mi = 0; mi < 2; ++mi) {
          const int row = mi * 16 + l16;
          pf[mi] = *(const bf16x8*)(pw + row * 64 + (((ks * 4 + quad) ^ (row & 7)) * 8));
        }
#pragma unroll
        for (int ni = 0; ni < 4; ++ni) {
          const int vrow = ni * 16 + l16;
          const int vblk = (half * 8 + ks * 4 + quad) ^ (vrow & 15);
          const bf16x8 vf = *(const bf16x8*)(Vs + vrow * 128 + vblk * 8);
          o[0][ni] = __builtin_amdgcn_mfma_f32_16x16x32_bf16(pf[0], vf, o[0][ni], 0, 0, 0);
          o[1][ni] = __builtin_amdgcn_mfma_f32_16x16x32_bf16(pf[1], vf, o[1][ni], 0, 0, 0);
        }
        osum[0] = __builtin_amdgcn_mfma_f32_16x16x32_bf16(pf[0], onef, osum[0], 0, 0, 0);
        osum[1] = __builtin_amdgcn_mfma_f32_16x16x32_bf16(pf[1], onef, osum[1], 0, 0, 0);
      }
    }
  }

  // epilogue: out = o / osum (lane-local), store ctx[b][s][h*64+d]
#pragma unroll
  for (int mi = 0; mi < 2; ++mi)
#pragma unroll
    for (int r = 0; r < 4; ++r) {
      const float inv = 1.0f / osum[mi][r];
      const int s = qt * 128 + wave * 32 + mi * 16 + quad * 4 + r;
#pragma unroll
      for (int ni = 0; ni < 4; ++ni)
        ctx[((size_t)b * S_DIM + s) * D_DIM + h * 64 + ni * 16 + l16] =
            (bf16)(o[mi][ni][r] * inv);
    }
}

// ------------------------------------------------------------------ launch
extern "C" void kernel_launch(void* const* d_in, const int* in_sizes, int n_in,
                              void* d_out, int out_size, void* d_ws, size_t ws_size,
                              hipStream_t stream) {
  const float* x    = (const float*)d_in[0];
  const float* mask = (const float*)d_in[1];
  const float* Wq   = (const float*)d_in[2];
  const float* bq   = (const float*)d_in[3];
  const float* Aq   = (const float*)d_in[4];
  const float* Bq   = (const float*)d_in[5];
  const float* Wk   = (const float*)d_in[6];
  const float* bk   = (const float*)d_in[7];
  const float* Wv   = (const float*)d_in[8];
  const float* bv   = (const float*)d_in[9];
  const float* Av   = (const float*)d_in[10];
  const float* Bv   = (const float*)d_in[11];
  const float* Wo   = (const float*)d_in[12];
  const float* bo   = (const float*)d_in[13];
  float* out = (float*)d_out;

  bf16* xb = (bf16*)d_ws;                       // 16 MB
  bf16* wq = xb + (size_t)M_DIM * D_DIM;        // 2 MB each
  bf16* wk = wq + (size_t)D_DIM * D_DIM;
  bf16* wv = wk + (size_t)D_DIM * D_DIM;
  bf16* wo = wv + (size_t)D_DIM * D_DIM;
  bf16* Qw = wo + (size_t)D_DIM * D_DIM;        // 16 MB each
  bf16* Kw = Qw + (size_t)M_DIM * D_DIM;
  bf16* Vw = Kw + (size_t)M_DIM * D_DIM;
  bf16* Cw = Vw + (size_t)M_DIM * D_DIM;

  convert_x_kernel<<<M_DIM * D_DIM / (256 * 8), 256, 0, stream>>>(x, xb);
  prep_w_kernel<<<D_DIM * D_DIM / 256, 256, 0, stream>>>(Wq, Aq, Bq, wq, 1);
  prep_w_kernel<<<D_DIM * D_DIM / 256, 256, 0, stream>>>(Wk, nullptr, nullptr, wk, 0);
  prep_w_kernel<<<D_DIM * D_DIM / 256, 256, 0, stream>>>(Wv, Av, Bv, wv, 1);
  prep_w_kernel<<<D_DIM * D_DIM / 256, 256, 0, stream>>>(Wo, nullptr, nullptr, wo, 0);

  gemm_nt_kernel<0><<<dim3(M_DIM / 128, D_DIM / 128), 256, 0, stream>>>(xb, wq, bq, Qw);
  gemm_nt_kernel<0><<<dim3(M_DIM / 128, D_DIM / 128), 256, 0, stream>>>(xb, wk, bk, Kw);
  gemm_nt_kernel<2><<<dim3(M_DIM / 128, D_DIM / 128), 256, 0, stream>>>(xb, wv, bv, Vw);

  attn_kernel<<<dim3(S_DIM / 128, B_DIM * H_DIM), 256, 0, stream>>>(Qw, Kw, Vw, mask, Cw);

  gemm_nt_kernel<1><<<dim3(M_DIM / 128, D_DIM / 128), 256, 0, stream>>>(Cw, wo, bo, out);
}

// Round 3
// 332.822 us; speedup vs baseline: 1.5896x; 1.1938x over previous
//
#include <hip/hip_runtime.h>
#include <cstdint>

// MultiHeadAttention with LoRA on Q/V.  B=4,S=2048,D=1024,H=16,HD=64,RANK=16,scale=2.0
// R3: S^T-formulation attention (packed b64 P-writes), 64 q-rows/wave,
// single-barrier double-buffered K/V staging; fused QKV GEMM (N=3072) with the
// same dbuf structure; Q pre-scaled by 0.125*log2e so softmax is exp2(s+cm).

#define D_DIM 1024
#define S_DIM 2048
#define B_DIM 4
#define H_DIM 16
#define HD_DIM 64
#define M_DIM 8192
#define LOG2E 1.44269504f

typedef __bf16 bf16;
typedef __bf16 bf16x4v __attribute__((ext_vector_type(4)));
typedef __bf16 bf16x8 __attribute__((ext_vector_type(8)));
typedef float f32x4 __attribute__((ext_vector_type(4)));

typedef __attribute__((address_space(1))) void* as1p;
typedef __attribute__((address_space(3))) void* as3p;

__device__ __forceinline__ void gll16(const void* g, void* l) {
  __builtin_amdgcn_global_load_lds((as1p)(g), (as3p)(l), 16, 0, 0);
}

// ---------------------------------------------------------------- conv x -> bf16
__global__ void convert_x_kernel(const float* __restrict__ x, bf16* __restrict__ xb) {
  const int i = (blockIdx.x * 256 + threadIdx.x) * 8;
  const float4 a = *(const float4*)(x + i);
  const float4 b = *(const float4*)(x + i + 4);
  bf16x8 o;
  o[0] = (bf16)a.x; o[1] = (bf16)a.y; o[2] = (bf16)a.z; o[3] = (bf16)a.w;
  o[4] = (bf16)b.x; o[5] = (bf16)b.y; o[6] = (bf16)b.z; o[7] = (bf16)b.w;
  *(bf16x8*)(xb + i) = o;
}

// ------------------------------------------------- W_eff = W + 2*Bm@A  -> bf16
__global__ void prep_w_kernel(const float* __restrict__ W, const float* __restrict__ A,
                              const float* __restrict__ Bm, bf16* __restrict__ out,
                              int use_lora) {
  const int i = blockIdx.x * 256 + threadIdx.x;
  const int n = i >> 10, k = i & (D_DIM - 1);
  float w = W[i];
  if (use_lora) {
    float acc = 0.f;
#pragma unroll
    for (int r = 0; r < 16; ++r) acc = fmaf(Bm[n * 16 + r], A[r * D_DIM + k], acc);
    w += 2.0f * acc;  // SCALING = 32/16
  }
  out[i] = (bf16)w;
}

// ----------------------------------------------- fused QKV GEMM (N=3072), dbuf
// Wqkv = [wq;wk;wv] rows.  Q gets *0.125*log2e and [B,H,S,64] layout; K same
// layout unscaled; V -> [B,H,64,S] transposed (b64-packed stores).
__global__ __launch_bounds__(256) void gemm_qkv_kernel(
    const bf16* __restrict__ X, const bf16* __restrict__ Wqkv,
    const float* __restrict__ bq, const float* __restrict__ bk,
    const float* __restrict__ bv, bf16* __restrict__ Qo, bf16* __restrict__ Ko,
    bf16* __restrict__ Vo) {
  __shared__ __attribute__((aligned(16))) bf16 As[2][128 * 64];
  __shared__ __attribute__((aligned(16))) bf16 Bs[2][128 * 64];
  const int tid = threadIdx.x;
  const int wave = tid >> 6, lane = tid & 63;
  const int quad = lane >> 4, l16 = lane & 15;
  const int m0 = blockIdx.x * 128, n0 = blockIdx.y * 128;
  const int wm = (wave >> 1) * 64, wn = (wave & 1) * 64;
  const int srow = lane >> 3, sblk = lane & 7;

  const f32x4 zero = {0.f, 0.f, 0.f, 0.f};
  f32x4 acc[4][4];
#pragma unroll
  for (int mi = 0; mi < 4; ++mi)
#pragma unroll
    for (int ni = 0; ni < 4; ++ni) acc[mi][ni] = zero;

  auto stage = [&](int kt) {
    const int buf = kt & 1, kb = kt * 64;
#pragma unroll
    for (int it = 0; it < 4; ++it) {
      const int c = it * 4 + wave;
      const int row = c * 8 + srow;
      const int b = sblk ^ (row & 7);
      gll16(X + (size_t)(m0 + row) * D_DIM + kb + b * 8, &As[buf][c * 512 + lane * 8]);
      gll16(Wqkv + (size_t)(n0 + row) * D_DIM + kb + b * 8, &Bs[buf][c * 512 + lane * 8]);
    }
  };
  stage(0);

  for (int kt = 0; kt < D_DIM / 64; ++kt) {
    __syncthreads();  // vmcnt drain: tile kt landed (all waves)
    if (kt + 1 < D_DIM / 64) stage(kt + 1);
    const bf16* as_ = &As[kt & 1][0];
    const bf16* bs_ = &Bs[kt & 1][0];
#pragma unroll
    for (int ks = 0; ks < 2; ++ks) {
      bf16x8 af[4], bfr[4];
#pragma unroll
      for (int mi = 0; mi < 4; ++mi) {
        const int row = wm + mi * 16 + l16;
        af[mi] = *(const bf16x8*)(as_ + row * 64 + (((ks * 4 + quad) ^ (row & 7)) * 8));
      }
#pragma unroll
      for (int ni = 0; ni < 4; ++ni) {
        const int row = wn + ni * 16 + l16;
        bfr[ni] = *(const bf16x8*)(bs_ + row * 64 + (((ks * 4 + quad) ^ (row & 7)) * 8));
      }
#pragma unroll
      for (int mi = 0; mi < 4; ++mi)
#pragma unroll
        for (int ni = 0; ni < 4; ++ni)
          acc[mi][ni] =
              __builtin_amdgcn_mfma_f32_16x16x32_bf16(af[mi], bfr[ni], acc[mi][ni], 0, 0, 0);
    }
  }

  const int sel = n0 >> 10;  // uniform per block: 0=Q 1=K 2=V
  const float* bp = (sel == 0) ? bq : (sel == 1) ? bk : bv;
  const float qs = 0.125f * LOG2E;

  if (sel == 2) {  // V^T: [B,H,64,S], s contiguous -> b64 packed stores
#pragma unroll
    for (int ni = 0; ni < 4; ++ni) {
      const int c = (n0 + wn + ni * 16 + l16) & 1023;
      const int h = c >> 6, hd = c & 63;
      const float bvv = bp[c];
#pragma unroll
      for (int mi = 0; mi < 4; ++mi) {
        const int row0 = m0 + wm + mi * 16 + quad * 4;
        const int b = row0 >> 11, s0 = row0 & (S_DIM - 1);
        bf16x4v pk;
#pragma unroll
        for (int r = 0; r < 4; ++r) pk[r] = (bf16)(acc[mi][ni][r] + bvv);
        *(bf16x4v*)(Vo + ((size_t)(b * H_DIM + h) * HD_DIM + hd) * S_DIM + s0) = pk;
      }
    }
  } else {
    bf16* O = (sel == 0) ? Qo : Ko;
#pragma unroll
    for (int ni = 0; ni < 4; ++ni) {
      const int c = (n0 + wn + ni * 16 + l16) & 1023;
      const int h = c >> 6, hd = c & 63;
      const float bvv = bp[c];
#pragma unroll
      for (int mi = 0; mi < 4; ++mi) {
#pragma unroll
        for (int r = 0; r < 4; ++r) {
          const int row = m0 + wm + mi * 16 + quad * 4 + r;
          const int b = row >> 11, s = row & (S_DIM - 1);
          float v = acc[mi][ni][r] + bvv;
          if (sel == 0) v *= qs;  // fold 1/sqrt(HD)*log2e into Q
          O[((size_t)(b * H_DIM + h) * S_DIM + s) * HD_DIM + hd] = (bf16)v;
        }
      }
    }
  }
}

// ------------------------------------------------ O-projection GEMM (fp32 out)
__global__ __launch_bounds__(256) void gemm_o_kernel(const bf16* __restrict__ X,
                                                     const bf16* __restrict__ W,
                                                     const float* __restrict__ bias,
                                                     float* __restrict__ out) {
  __shared__ __attribute__((aligned(16))) bf16 As[2][128 * 64];
  __shared__ __attribute__((aligned(16))) bf16 Bs[2][128 * 64];
  const int tid = threadIdx.x;
  const int wave = tid >> 6, lane = tid & 63;
  const int quad = lane >> 4, l16 = lane & 15;
  const int m0 = blockIdx.x * 128, n0 = blockIdx.y * 128;
  const int wm = (wave >> 1) * 64, wn = (wave & 1) * 64;
  const int srow = lane >> 3, sblk = lane & 7;

  const f32x4 zero = {0.f, 0.f, 0.f, 0.f};
  f32x4 acc[4][4];
#pragma unroll
  for (int mi = 0; mi < 4; ++mi)
#pragma unroll
    for (int ni = 0; ni < 4; ++ni) acc[mi][ni] = zero;

  auto stage = [&](int kt) {
    const int buf = kt & 1, kb = kt * 64;
#pragma unroll
    for (int it = 0; it < 4; ++it) {
      const int c = it * 4 + wave;
      const int row = c * 8 + srow;
      const int b = sblk ^ (row & 7);
      gll16(X + (size_t)(m0 + row) * D_DIM + kb + b * 8, &As[buf][c * 512 + lane * 8]);
      gll16(W + (size_t)(n0 + row) * D_DIM + kb + b * 8, &Bs[buf][c * 512 + lane * 8]);
    }
  };
  stage(0);

  for (int kt = 0; kt < D_DIM / 64; ++kt) {
    __syncthreads();
    if (kt + 1 < D_DIM / 64) stage(kt + 1);
    const bf16* as_ = &As[kt & 1][0];
    const bf16* bs_ = &Bs[kt & 1][0];
#pragma unroll
    for (int ks = 0; ks < 2; ++ks) {
      bf16x8 af[4], bfr[4];
#pragma unroll
      for (int mi = 0; mi < 4; ++mi) {
        const int row = wm + mi * 16 + l16;
        af[mi] = *(const bf16x8*)(as_ + row * 64 + (((ks * 4 + quad) ^ (row & 7)) * 8));
      }
#pragma unroll
      for (int ni = 0; ni < 4; ++ni) {
        const int row = wn + ni * 16 + l16;
        bfr[ni] = *(const bf16x8*)(bs_ + row * 64 + (((ks * 4 + quad) ^ (row & 7)) * 8));
      }
#pragma unroll
      for (int mi = 0; mi < 4; ++mi)
#pragma unroll
        for (int ni = 0; ni < 4; ++ni)
          acc[mi][ni] =
              __builtin_amdgcn_mfma_f32_16x16x32_bf16(af[mi], bfr[ni], acc[mi][ni], 0, 0, 0);
    }
  }
#pragma unroll
  for (int ni = 0; ni < 4; ++ni) {
    const int col = n0 + wn + ni * 16 + l16;
    const float bv = bias[col];
#pragma unroll
    for (int mi = 0; mi < 4; ++mi)
#pragma unroll
      for (int r = 0; r < 4; ++r) {
        const int row = m0 + wm + mi * 16 + quad * 4 + r;
        out[(size_t)row * D_DIM + col] = acc[mi][ni][r] + bv;
      }
  }
}

// ------------------------------------------------------------------ attention
// Q,K [B,H,S,64] (Q pre-scaled by 0.125*log2e); Vt [B,H,64,S]; mask [B,S];
// ctx [B,S,D] bf16.  256 q/block (4 waves x 64), KV tile 64, double-buffered.
// S^T = mfma(kf, qf): C-layout col=q, row=kv => 4 consecutive kv per reg-quad
// => packed b64 P-writes; PV A-frag read stays contiguous b128.
// Softmax: p = exp2(s + mask*log2e - 16); out = (P V)/(P 1) — shift cancels.
__global__ __launch_bounds__(256, 2) void attn_kernel(const bf16* __restrict__ Q,
                                                      const bf16* __restrict__ K,
                                                      const bf16* __restrict__ Vt,
                                                      const float* __restrict__ mask,
                                                      bf16* __restrict__ ctx) {
  __shared__ __attribute__((aligned(16))) bf16 Ks[2][64 * 64];
  __shared__ __attribute__((aligned(16))) bf16 Vs[2][64 * 64];
  __shared__ __attribute__((aligned(16))) bf16 Ps[4][64 * 64];
  __shared__ __attribute__((aligned(16))) float cms[S_DIM];

  const int tid = threadIdx.x;
  const int wave = tid >> 6, lane = tid & 63;
  const int quad = lane >> 4, l16 = lane & 15;
  const int bh = blockIdx.y, b = bh >> 4, h = bh & 15;
  const int qt = blockIdx.x;  // 256 q-rows per block

  // Q fragments in registers: 64 rows per wave
  const bf16* Qg = Q + ((size_t)bh * S_DIM + qt * 256 + wave * 64) * HD_DIM;
  bf16x8 qf[4][2];
#pragma unroll
  for (int nq = 0; nq < 4; ++nq)
#pragma unroll
    for (int ks = 0; ks < 2; ++ks)
      qf[nq][ks] = *(const bf16x8*)(Qg + (nq * 16 + l16) * HD_DIM + ks * 32 + quad * 8);

  // stage mask -> cms = mask*log2e - 16  (once)
  {
    const float* mp = mask + b * S_DIM + tid * 8;
    const float4 a = *(const float4*)(mp);
    const float4 c = *(const float4*)(mp + 4);
    f32x4 r0 = {fmaf(a.x, LOG2E, -16.f), fmaf(a.y, LOG2E, -16.f),
                fmaf(a.z, LOG2E, -16.f), fmaf(a.w, LOG2E, -16.f)};
    f32x4 r1 = {fmaf(c.x, LOG2E, -16.f), fmaf(c.y, LOG2E, -16.f),
                fmaf(c.z, LOG2E, -16.f), fmaf(c.w, LOG2E, -16.f)};
    *(f32x4*)(cms + tid * 8) = r0;
    *(f32x4*)(cms + tid * 8 + 4) = r1;
  }

  bf16x8 onef;
#pragma unroll
  for (int j = 0; j < 8; ++j) onef[j] = (bf16)1.0f;

  const f32x4 zero = {0.f, 0.f, 0.f, 0.f};
  f32x4 o[4][4], osum[4];
#pragma unroll
  for (int nq = 0; nq < 4; ++nq) {
    osum[nq] = zero;
#pragma unroll
    for (int nh = 0; nh < 4; ++nh) o[nq][nh] = zero;
  }

  const bf16* Kg0 = K + (size_t)bh * S_DIM * HD_DIM;
  const bf16* Vg0 = Vt + (size_t)bh * HD_DIM * S_DIM;

  auto stage = [&](int t) {
    const int buf = t & 1;
    const bf16* Kg = Kg0 + (size_t)t * 64 * HD_DIM;
    const bf16* Vg = Vg0 + t * 64;
#pragma unroll
    for (int it = 0; it < 2; ++it) {
      const int c = it * 4 + wave;  // 0..7 chunks of 1024B
      const int row = c * 8 + (lane >> 3);
      const int blk = (lane & 7) ^ (row & 7);
      gll16(Kg + (size_t)row * HD_DIM + blk * 8, &Ks[buf][c * 512 + lane * 8]);
      gll16(Vg + (size_t)row * S_DIM + blk * 8, &Vs[buf][c * 512 + lane * 8]);
    }
  };
  stage(0);

  bf16* pw = &Ps[wave][0];
  for (int t = 0; t < S_DIM / 64; ++t) {
    __syncthreads();  // per-wave vmcnt drain at barrier: tile t + cms ready
    if (t + 1 < S_DIM / 64) stage(t + 1);
    const bf16* ks_ = &Ks[t & 1][0];
    const bf16* vs_ = &Vs[t & 1][0];

    // ---- S^T tiles + exp2 + packed P write
#pragma unroll
    for (int mt = 0; mt < 4; ++mt) {  // kv 16-row groups
      f32x4 sc[4];
#pragma unroll
      for (int nq = 0; nq < 4; ++nq) sc[nq] = zero;
#pragma unroll
      for (int ks = 0; ks < 2; ++ks) {
        const int row = mt * 16 + l16;  // kv
        const bf16x8 kf =
            *(const bf16x8*)(ks_ + row * 64 + (((ks * 4 + quad) ^ (row & 7)) * 8));
#pragma unroll
        for (int nq = 0; nq < 4; ++nq)
          sc[nq] = __builtin_amdgcn_mfma_f32_16x16x32_bf16(kf, qf[nq][ks], sc[nq], 0, 0, 0);
      }
      const f32x4 cm = *(const f32x4*)(cms + t * 64 + mt * 16 + quad * 4);  // broadcast
      const int kvblk = mt * 2 + (quad >> 1);
#pragma unroll
      for (int nq = 0; nq < 4; ++nq) {
        bf16x4v pk;
#pragma unroll
        for (int r = 0; r < 4; ++r) pk[r] = (bf16)exp2f(sc[nq][r] + cm[r]);
        const int q = nq * 16 + l16;
        *(bf16x4v*)(pw + q * 64 + ((kvblk ^ (q & 7)) * 8) + (quad & 1) * 4) = pk;
      }
    }
    // same-wave producer/consumer: compiler inserts lgkmcnt wait (may-alias)

    // ---- O += P V ; osum += P 1
#pragma unroll
    for (int ks = 0; ks < 2; ++ks) {
      bf16x8 pf[4];
#pragma unroll
      for (int nq = 0; nq < 4; ++nq) {
        const int q = nq * 16 + l16;
        pf[nq] = *(const bf16x8*)(pw + q * 64 + (((ks * 4 + quad) ^ (q & 7)) * 8));
      }
#pragma unroll
      for (int nh = 0; nh < 4; ++nh) {
        const int vrow = nh * 16 + l16;
        const bf16x8 vf =
            *(const bf16x8*)(vs_ + vrow * 64 + (((ks * 4 + quad) ^ (vrow & 7)) * 8));
#pragma unroll
        for (int nq = 0; nq < 4; ++nq)
          o[nq][nh] = __builtin_amdgcn_mfma_f32_16x16x32_bf16(pf[nq], vf, o[nq][nh], 0, 0, 0);
      }
#pragma unroll
      for (int nq = 0; nq < 4; ++nq)
        osum[nq] = __builtin_amdgcn_mfma_f32_16x16x32_bf16(pf[nq], onef, osum[nq], 0, 0, 0);
    }
  }

  // epilogue: out = o / osum (lane-local)
#pragma unroll
  for (int nq = 0; nq < 4; ++nq)
#pragma unroll
    for (int r = 0; r < 4; ++r) {
      const float inv = 1.0f / osum[nq][r];
      const int s = qt * 256 + wave * 64 + nq * 16 + quad * 4 + r;
#pragma unroll
      for (int nh = 0; nh < 4; ++nh)
        ctx[((size_t)b * S_DIM + s) * D_DIM + h * 64 + nh * 16 + l16] =
            (bf16)(o[nq][nh][r] * inv);
    }
}

// ------------------------------------------------------------------ launch
extern "C" void kernel_launch(void* const* d_in, const int* in_sizes, int n_in,
                              void* d_out, int out_size, void* d_ws, size_t ws_size,
                              hipStream_t stream) {
  const float* x    = (const float*)d_in[0];
  const float* mask = (const float*)d_in[1];
  const float* Wq   = (const float*)d_in[2];
  const float* bq   = (const float*)d_in[3];
  const float* Aq   = (const float*)d_in[4];
  const float* Bq   = (const float*)d_in[5];
  const float* Wk   = (const float*)d_in[6];
  const float* bk   = (const float*)d_in[7];
  const float* Wv   = (const float*)d_in[8];
  const float* bv   = (const float*)d_in[9];
  const float* Av   = (const float*)d_in[10];
  const float* Bv   = (const float*)d_in[11];
  const float* Wo   = (const float*)d_in[12];
  const float* bo   = (const float*)d_in[13];
  float* out = (float*)d_out;

  // workspace (xb aliased by Cw after QKV GEMM): ~75.5 MB total
  bf16* xb   = (bf16*)d_ws;                        // 16.8 MB (dead after QKV GEMM)
  bf16* wqkv = xb + (size_t)M_DIM * D_DIM;         // 6.3 MB  [wq;wk;wv]
  bf16* wo   = wqkv + (size_t)3 * D_DIM * D_DIM;   // 2.1 MB
  bf16* Qw   = wo + (size_t)D_DIM * D_DIM;         // 16.8 MB each
  bf16* Kw   = Qw + (size_t)M_DIM * D_DIM;
  bf16* Vw   = Kw + (size_t)M_DIM * D_DIM;
  bf16* Cw   = xb;                                 // alias: ctx reuses xb

  convert_x_kernel<<<M_DIM * D_DIM / (256 * 8), 256, 0, stream>>>(x, xb);
  prep_w_kernel<<<D_DIM * D_DIM / 256, 256, 0, stream>>>(Wq, Aq, Bq, wqkv, 1);
  prep_w_kernel<<<D_DIM * D_DIM / 256, 256, 0, stream>>>(Wk, nullptr, nullptr,
                                                         wqkv + (size_t)D_DIM * D_DIM, 0);
  prep_w_kernel<<<D_DIM * D_DIM / 256, 256, 0, stream>>>(Wv, Av, Bv,
                                                         wqkv + (size_t)2 * D_DIM * D_DIM, 1);
  prep_w_kernel<<<D_DIM * D_DIM / 256, 256, 0, stream>>>(Wo, nullptr, nullptr, wo, 0);

  gemm_qkv_kernel<<<dim3(M_DIM / 128, 3 * D_DIM / 128), 256, 0, stream>>>(
      xb, wqkv, bq, bk, bv, Qw, Kw, Vw);

  attn_kernel<<<dim3(S_DIM / 256, B_DIM * H_DIM), 256, 0, stream>>>(Qw, Kw, Vw, mask, Cw);

  gemm_o_kernel<<<dim3(M_DIM / 128, D_DIM / 128), 256, 0, stream>>>(Cw, wo, bo, out);
}